// Round 1
// baseline (531.870 us; speedup 1.0000x reference)
//
#include <hip/hip_runtime.h>
#include <stdint.h>

#define B_BATCH 64
#define L_SEQ 2048
#define E_DIM 1024
#define A_DIM 512

typedef __attribute__((ext_vector_type(4))) float f32x4;
typedef __attribute__((ext_vector_type(8))) short bf16x8;
typedef __attribute__((ext_vector_type(2))) unsigned int u32x2;

__device__ __forceinline__ unsigned short f2bf(float f) {
  unsigned u = __float_as_uint(f);
  u = (u + 0x7fffu + ((u >> 16) & 1u)) >> 16;  // RNE
  return (unsigned short)u;
}

__device__ __forceinline__ u32x2 packbf(f32x4 v) {
  u32x2 r;
  r.x = (unsigned)f2bf(v.x) | ((unsigned)f2bf(v.y) << 16);
  r.y = (unsigned)f2bf(v.z) | ((unsigned)f2bf(v.w) << 16);
  return r;
}

// k-group permutation: 8B unit position of k-group kg (kg = k>>2, k in [0,32))
// memory order [kg0,kg4,kg1,kg5,kg2,kg6,kg3,kg7] so one ds_read_b128 at +g*16
// yields frag elems k = {4g..4g+3, 16+4g..16+4g+3} (two stacked 16x16x16 halves).
__device__ __forceinline__ int kperm(int kg) { return (kg & 3) * 2 + (kg >> 2); }

__device__ __forceinline__ void gload_lds16(const void* g, void* l) {
  __builtin_amdgcn_global_load_lds(
      (const __attribute__((address_space(1))) unsigned int*)(uintptr_t)g,
      (__attribute__((address_space(3))) unsigned int*)(unsigned)(uintptr_t)l,
      16, 0, 0);
}

#define ASTRIDE 80                      // bytes per LDS row: 32 bf16 used + 16B pad (bank spread)
#define ABYTES (128 * ASTRIDE)          // 10240
#define BBYTES (512 * ASTRIDE)          // 40960
#define BUFBYTES (ABYTES + BBYTES)      // 51200
#define BCHUNK 40960                    // ws_B bytes per K-step chunk

// ---------------- K0: convert We_w (fp32 [1024,512]) -> ws_B bf16 staged image --------------
__global__ void prep_we_kernel(const float* __restrict__ We, char* __restrict__ wsB) {
  int t = blockIdx.x * 256 + threadIdx.x;  // 131072 threads
  int n = t & 511;
  int kgl = t >> 9;  // 0..255, covers e0 = kgl*4
  int e0 = kgl * 4;
  int kb = e0 >> 5;
  int kg = (e0 & 31) >> 2;
  unsigned lo = (unsigned)f2bf(We[(size_t)(e0 + 0) * A_DIM + n]) |
                ((unsigned)f2bf(We[(size_t)(e0 + 1) * A_DIM + n]) << 16);
  unsigned hi = (unsigned)f2bf(We[(size_t)(e0 + 2) * A_DIM + n]) |
                ((unsigned)f2bf(We[(size_t)(e0 + 3) * A_DIM + n]) << 16);
  u32x2 val; val.x = lo; val.y = hi;
  *(u32x2*)(wsB + (size_t)kb * BCHUNK + n * ASTRIDE + kperm(kg) * 8) = val;
}

// ---------------- K1: dcomb[b][a] = decoder_hidden[b]·Wd_w[:,a] + Wd_b[a] + We_b[a] ---------
__global__ void dec_comb_kernel(const float* __restrict__ dh, const float* __restrict__ Wd,
                                const float* __restrict__ Wdb, const float* __restrict__ Web,
                                float* __restrict__ dcomb) {
  __shared__ float sh[1024];
  const int b = blockIdx.x, tid = threadIdx.x;
  for (int i = tid; i < 1024; i += 256) sh[i] = dh[b * 1024 + i];
  __syncthreads();
#pragma unroll
  for (int rep = 0; rep < 2; ++rep) {
    const int a = tid + rep * 256;
    float acc = Wdb[a] + Web[a];
#pragma unroll 4
    for (int e = 0; e < 1024; ++e) acc += sh[e] * Wd[(size_t)e * A_DIM + a];
    dcomb[b * A_DIM + a] = acc;
  }
}

// ---------------- K2: fused score GEMM: scores[row] = sum_a relu(enc·We + db)·Wf ------------
// block: 128 rows x 512 cols, 8 waves (512 thr), wave = 128 rows x 64 cols,
// mfma_f32_16x16x32_bf16, BK=32, double-buffered LDS.
__global__ __launch_bounds__(512, 2) void score_gemm_kernel(
    const float* __restrict__ enc, const char* __restrict__ wsB,
    const float* __restrict__ dcomb, const float* __restrict__ wf,
    float* __restrict__ scoreOut) {
  __shared__ __align__(16) char smem[2 * BUFBYTES];
  __shared__ float s_score[128];

  const int tid = threadIdx.x;
  const int lane = tid & 63;
  const int w = tid >> 6;
  const int g = lane >> 4;
  const int nl = lane & 15;
  const int row0 = blockIdx.x * 128;
  const int bb = row0 >> 11;  // batch index

  if (tid < 128) s_score[tid] = 0.0f;

  const float* encA = enc + (size_t)row0 * E_DIM;

  int aoff[8];
  int boff[4];
#pragma unroll
  for (int rt = 0; rt < 8; ++rt) aoff[rt] = (rt * 16 + nl) * ASTRIDE + g * 16;
#pragma unroll
  for (int ct = 0; ct < 4; ++ct) boff[ct] = ABYTES + (w * 64 + ct * 16 + nl) * ASTRIDE + g * 16;

  // A staging decomposition: thread handles (row, kgroup) = (id>>3, id&7), id = tid, tid+512
  const int ar0 = tid >> 3, akg = tid & 7;
  const int ar1 = ar0 + 64;
  const int aw0 = ar0 * ASTRIDE + kperm(akg) * 8;
  const int aw1 = ar1 * ASTRIDE + kperm(akg) * 8;
  const float* asrc0 = encA + (size_t)ar0 * E_DIM + akg * 4;
  const float* asrc1 = encA + (size_t)ar1 * E_DIM + akg * 4;

  f32x4 acc[8][4];
#pragma unroll
  for (int rt = 0; rt < 8; ++rt)
#pragma unroll
    for (int ct = 0; ct < 4; ++ct) {
      f32x4 z = {0.f, 0.f, 0.f, 0.f};
      acc[rt][ct] = z;
    }

  // prologue: stage K-step 0 into buffer 0
  {
#pragma unroll
    for (int c = 0; c < 5; ++c)
      gload_lds16(wsB + c * 8192 + w * 1024 + lane * 16,
                  smem + ABYTES + c * 8192 + w * 1024);
    f32x4 va = *(const f32x4*)(asrc0);
    f32x4 vb = *(const f32x4*)(asrc1);
    *(u32x2*)(smem + aw0) = packbf(va);
    *(u32x2*)(smem + aw1) = packbf(vb);
  }
  __syncthreads();

  f32x4 va, vb;
  for (int step = 0; step < 32; ++step) {
    const char* cur = smem + (step & 1) * BUFBYTES;
    char* nxt = smem + ((step + 1) & 1) * BUFBYTES;
    if (step < 31) {
      const int kb = step + 1;
#pragma unroll
      for (int c = 0; c < 5; ++c)
        gload_lds16(wsB + (size_t)kb * BCHUNK + c * 8192 + w * 1024 + lane * 16,
                    nxt + ABYTES + c * 8192 + w * 1024);
      va = *(const f32x4*)(asrc0 + kb * 32);
      vb = *(const f32x4*)(asrc1 + kb * 32);
    }
    bf16x8 bfr[4], afr[8];
#pragma unroll
    for (int ct = 0; ct < 4; ++ct) bfr[ct] = *(const bf16x8*)(cur + boff[ct]);
#pragma unroll
    for (int rt = 0; rt < 8; ++rt) afr[rt] = *(const bf16x8*)(cur + aoff[rt]);
#pragma unroll
    for (int rt = 0; rt < 8; ++rt)
#pragma unroll
      for (int ct = 0; ct < 4; ++ct)
        acc[rt][ct] = __builtin_amdgcn_mfma_f32_16x16x32_bf16(afr[rt], bfr[ct],
                                                              acc[rt][ct], 0, 0, 0);
    if (step < 31) {
      *(u32x2*)(nxt + aw0) = packbf(va);
      *(u32x2*)(nxt + aw1) = packbf(vb);
    }
    __syncthreads();
  }

  // epilogue: h = relu(acc + db), p = h·wf, reduce over the 512 cols
  float db[4], wv[4];
#pragma unroll
  for (int ct = 0; ct < 4; ++ct) {
    int a = w * 64 + ct * 16 + nl;
    db[ct] = dcomb[bb * A_DIM + a];
    wv[ct] = wf[a];
  }
#pragma unroll
  for (int rt = 0; rt < 8; ++rt) {
#pragma unroll
    for (int r = 0; r < 4; ++r) {
      float p = 0.f;
#pragma unroll
      for (int ct = 0; ct < 4; ++ct) {
        float h = acc[rt][ct][r] + db[ct];
        h = h > 0.f ? h : 0.f;
        p += h * wv[ct];
      }
      p += __shfl_xor(p, 1);
      p += __shfl_xor(p, 2);
      p += __shfl_xor(p, 4);
      p += __shfl_xor(p, 8);
      if (nl == 0) atomicAdd(&s_score[rt * 16 + g * 4 + r], p);
    }
  }
  __syncthreads();
  if (tid < 128) scoreOut[row0 + tid] = s_score[tid];
}

// ---------------- K3: softmax over L per batch, in place ------------------------------------
__global__ void softmax_kernel(float* __restrict__ attn) {
  __shared__ float red[8];
  const int b = blockIdx.x, tid = threadIdx.x;
  float* p = attn + b * L_SEQ;
  float v[8];
  float m = -1e30f;
#pragma unroll
  for (int i = 0; i < 8; ++i) {
    v[i] = p[tid + i * 256];
    m = fmaxf(m, v[i]);
  }
#pragma unroll
  for (int off = 1; off < 64; off <<= 1) m = fmaxf(m, __shfl_xor(m, off));
  const int wid = tid >> 6;
  if ((tid & 63) == 0) red[wid] = m;
  __syncthreads();
  m = fmaxf(fmaxf(red[0], red[1]), fmaxf(red[2], red[3]));
  float s = 0.f;
#pragma unroll
  for (int i = 0; i < 8; ++i) {
    v[i] = __expf(v[i] - m);
    s += v[i];
  }
#pragma unroll
  for (int off = 1; off < 64; off <<= 1) s += __shfl_xor(s, off);
  __syncthreads();
  if ((tid & 63) == 0) red[4 + wid] = s;
  __syncthreads();
  const float inv = 1.0f / (red[4] + red[5] + red[6] + red[7]);
#pragma unroll
  for (int i = 0; i < 8; ++i) p[tid + i * 256] = v[i] * inv;
}

// ---------------- K4: weighted[b][e] = sum_l alpha[b][l] * enc[b][l][e] ---------------------
__global__ void weighted_kernel(const float* __restrict__ enc, const float* __restrict__ alpha,
                                float* __restrict__ outW) {
  __shared__ float sa[256];
  const int bid = blockIdx.x;  // 512 = 64 b * 8 l-segments
  const int b = bid >> 3, ls = bid & 7;
  const int tid = threadIdx.x;
  sa[tid] = alpha[b * L_SEQ + ls * 256 + tid];
  __syncthreads();
  const f32x4* ep = (const f32x4*)(enc + ((size_t)(b * L_SEQ + ls * 256)) * E_DIM) + tid;
  f32x4 acc = {0.f, 0.f, 0.f, 0.f};
#pragma unroll 4
  for (int il = 0; il < 256; ++il) {
    f32x4 v = ep[(size_t)il * 256];
    float al = sa[il];
    acc.x += al * v.x;
    acc.y += al * v.y;
    acc.z += al * v.z;
    acc.w += al * v.w;
  }
  float* o = outW + b * E_DIM + tid * 4;
  atomicAdd(o + 0, acc.x);
  atomicAdd(o + 1, acc.y);
  atomicAdd(o + 2, acc.z);
  atomicAdd(o + 3, acc.w);
}

extern "C" void kernel_launch(void* const* d_in, const int* in_sizes, int n_in,
                              void* d_out, int out_size, void* d_ws, size_t ws_size,
                              hipStream_t stream) {
  const float* enc = (const float*)d_in[0];
  const float* dh = (const float*)d_in[1];
  const float* WeW = (const float*)d_in[2];
  const float* WeB = (const float*)d_in[3];
  const float* WdW = (const float*)d_in[4];
  const float* WdB = (const float*)d_in[5];
  const float* WfW = (const float*)d_in[6];
  // Wf_b (d_in[7]) is irrelevant: softmax is shift-invariant and attn isn't an output.

  float* out = (float*)d_out;
  float* outW = out;                      // weighted: 64*1024
  float* attn = out + B_BATCH * E_DIM;    // scores -> alpha: 64*2048

  char* wsB = (char*)d_ws;                                  // 32 * 40960 = 1.25 MB
  float* dcomb = (float*)((char*)d_ws + 32 * (size_t)BCHUNK);  // 64*512 fp32

  if (ws_size < 32 * (size_t)BCHUNK + (size_t)B_BATCH * A_DIM * sizeof(float)) return;

  hipMemsetAsync(outW, 0, (size_t)B_BATCH * E_DIM * sizeof(float), stream);
  prep_we_kernel<<<512, 256, 0, stream>>>(WeW, wsB);
  dec_comb_kernel<<<B_BATCH, 256, 0, stream>>>(dh, WdW, WdB, WeB, dcomb);
  score_gemm_kernel<<<(B_BATCH * L_SEQ) / 128, 512, 0, stream>>>(enc, wsB, dcomb, WfW, attn);
  softmax_kernel<<<B_BATCH, 256, 0, stream>>>(attn);
  weighted_kernel<<<B_BATCH * 8, 256, 0, stream>>>(enc, attn, outW);
}

// Round 2
// 434.245 us; speedup vs baseline: 1.2248x; 1.2248x over previous
//
#include <hip/hip_runtime.h>
#include <stdint.h>

#define B_BATCH 64
#define L_SEQ 2048
#define E_DIM 1024
#define A_DIM 512

typedef __attribute__((ext_vector_type(4))) float f32x4;
typedef __attribute__((ext_vector_type(8))) short bf16x8;
typedef __attribute__((ext_vector_type(2))) unsigned int u32x2;
typedef __attribute__((ext_vector_type(4))) unsigned int u32x4;

__device__ __forceinline__ unsigned short f2bf(float f) {
  unsigned u = __float_as_uint(f);
  u = (u + 0x7fffu + ((u >> 16) & 1u)) >> 16;  // RNE
  return (unsigned short)u;
}

__device__ __forceinline__ u32x2 packbf(f32x4 v) {
  u32x2 r;
  r.x = (unsigned)f2bf(v.x) | ((unsigned)f2bf(v.y) << 16);
  r.y = (unsigned)f2bf(v.z) | ((unsigned)f2bf(v.w) << 16);
  return r;
}

// k-group permutation: 8B unit position of k-group kg (kg = k>>2, k in [0,32))
// memory order [kg0,kg4,kg1,kg5,kg2,kg6,kg3,kg7]: ds_read_b128 at +g*16 yields
// frag elems k = {4g..4g+3, 16+4g..16+4g+3} (two stacked 16x16x16 halves).
__device__ __forceinline__ int kperm(int kg) { return (kg & 3) * 2 + (kg >> 2); }

__device__ __forceinline__ void gload_lds16(const void* g, void* l) {
  __builtin_amdgcn_global_load_lds(
      (const __attribute__((address_space(1))) unsigned int*)(uintptr_t)g,
      (__attribute__((address_space(3))) unsigned int*)(unsigned)(uintptr_t)l,
      16, 0, 0);
}

#define ASTRIDE 80                 // bytes per LDS row: 32 bf16 + 16B pad (bank spread)
#define ABYTES (128 * ASTRIDE)     // 10240
#define NB_COLS 256                // N-split: cols per block
#define BBYTES (NB_COLS * ASTRIDE) // 20480
#define BUFBYTES (ABYTES + BBYTES) // 30720
#define BCHUNK 40960               // ws_B bytes per K-step chunk (full 512 cols)

// ---------------- K0: convert We_w (fp32 [1024,512]) -> ws_B bf16 staged image --------------
__global__ void prep_we_kernel(const float* __restrict__ We, char* __restrict__ wsB) {
  int t = blockIdx.x * 256 + threadIdx.x;  // 131072 threads
  int n = t & 511;
  int kgl = t >> 9;  // 0..255, e0 = kgl*4
  int e0 = kgl * 4;
  int kb = e0 >> 5;
  int kg = (e0 & 31) >> 2;
  unsigned lo = (unsigned)f2bf(We[(size_t)(e0 + 0) * A_DIM + n]) |
                ((unsigned)f2bf(We[(size_t)(e0 + 1) * A_DIM + n]) << 16);
  unsigned hi = (unsigned)f2bf(We[(size_t)(e0 + 2) * A_DIM + n]) |
                ((unsigned)f2bf(We[(size_t)(e0 + 3) * A_DIM + n]) << 16);
  u32x2 val; val.x = lo; val.y = hi;
  *(u32x2*)(wsB + (size_t)kb * BCHUNK + n * ASTRIDE + kperm(kg) * 8) = val;
}

// ---------------- K1: dcomb[b][a] = decoder_hidden[b]·Wd_w[:,a] + Wd_b[a] + We_b[a] ---------
__global__ void dec_comb_kernel(const float* __restrict__ dh, const float* __restrict__ Wd,
                                const float* __restrict__ Wdb, const float* __restrict__ Web,
                                float* __restrict__ dcomb) {
  __shared__ float sh[1024];
  const int b = blockIdx.x, tid = threadIdx.x;
  for (int i = tid; i < 1024; i += 256) sh[i] = dh[b * 1024 + i];
  __syncthreads();
  const int a = blockIdx.y * 256 + tid;
  float acc = Wdb[a] + Web[a];
#pragma unroll 4
  for (int e = 0; e < 1024; ++e) acc += sh[e] * Wd[(size_t)e * A_DIM + a];
  dcomb[b * A_DIM + a] = acc;
}

// ---------------- K2: fused score GEMM: scores[row] += sum_a relu(enc·We + db)·Wf -----------
// block: 128 rows x 256 cols (N-split of 2), 4 waves (256 thr), wave = 128x64,
// mfma_f32_16x16x32_bf16, BK=32, double-buffered LDS, 2 blocks/CU for overlap.
__global__ __launch_bounds__(256, 2) void score_gemm_kernel(
    const float* __restrict__ enc, const char* __restrict__ wsB,
    const float* __restrict__ dcomb, const float* __restrict__ wf,
    float* __restrict__ scoreOut) {
  __shared__ __align__(16) char smem[2 * BUFBYTES];
  __shared__ float s_score[128];

  const int tid = threadIdx.x;
  const int lane = tid & 63;
  const int w = tid >> 6;      // 0..3
  const int g = lane >> 4;
  const int nl = lane & 15;

  // XCD-aware swizzle: keep both col-splits of a row-block on the SAME XCD,
  // temporally adjacent, so the second split's A-read hits L2. 2048 % 8 == 0.
  const int bid = (int)blockIdx.x;
  const int lbid = (bid & 7) * 256 + (bid >> 3);
  const int split = lbid & 1;           // col half: 0 or 1
  const int rowblk = lbid >> 1;         // 0..1023
  const int row0 = rowblk * 128;
  const int bb = row0 >> 11;            // batch index

  if (tid < 128) s_score[tid] = 0.0f;

  const float* encA = enc + (size_t)row0 * E_DIM;

  int aoff[8];
  int boff[4];
#pragma unroll
  for (int rt = 0; rt < 8; ++rt) aoff[rt] = (rt * 16 + nl) * ASTRIDE + g * 16;
#pragma unroll
  for (int ct = 0; ct < 4; ++ct) boff[ct] = ABYTES + (w * 64 + ct * 16 + nl) * ASTRIDE + g * 16;

  // A staging: thread -> (row r = tid>>2 and r+64, chunk c = tid&3).
  // Chunk c (16B) = kg pair {c, c+4} = k {4c..4c+3} and {16+4c..16+4c+3}.
  const int ar0 = tid >> 2, ac = tid & 3;
  const int ar1 = ar0 + 64;
  const int aw0 = ar0 * ASTRIDE + ac * 16;
  const int aw1 = ar1 * ASTRIDE + ac * 16;
  const float* asrc0 = encA + (size_t)ar0 * E_DIM + ac * 4;   // +16 for hi half
  const float* asrc1 = encA + (size_t)ar1 * E_DIM + ac * 4;

  const char* bsrc = wsB + split * (NB_COLS * ASTRIDE);

  f32x4 acc[8][4];
#pragma unroll
  for (int rt = 0; rt < 8; ++rt)
#pragma unroll
    for (int ct = 0; ct < 4; ++ct) {
      f32x4 z = {0.f, 0.f, 0.f, 0.f};
      acc[rt][ct] = z;
    }

  // prologue: stage K-step 0 into buffer 0
  {
#pragma unroll
    for (int c = 0; c < 5; ++c)
      gload_lds16(bsrc + c * 4096 + w * 1024 + lane * 16,
                  smem + ABYTES + c * 4096 + w * 1024);
    f32x4 va = *(const f32x4*)(asrc0);
    f32x4 vb = *(const f32x4*)(asrc0 + 16);
    f32x4 vc = *(const f32x4*)(asrc1);
    f32x4 vd = *(const f32x4*)(asrc1 + 16);
    u32x2 lo0 = packbf(va), hi0 = packbf(vb), lo1 = packbf(vc), hi1 = packbf(vd);
    u32x4 w0; w0.x = lo0.x; w0.y = lo0.y; w0.z = hi0.x; w0.w = hi0.y;
    u32x4 w1; w1.x = lo1.x; w1.y = lo1.y; w1.z = hi1.x; w1.w = hi1.y;
    *(u32x4*)(smem + aw0) = w0;
    *(u32x4*)(smem + aw1) = w1;
  }
  __syncthreads();

  f32x4 va, vb, vc, vd;
  for (int step = 0; step < 32; ++step) {
    const char* cur = smem + (step & 1) * BUFBYTES;
    char* nxt = smem + ((step + 1) & 1) * BUFBYTES;
    if (step < 31) {
      const int kb = step + 1;
#pragma unroll
      for (int c = 0; c < 5; ++c)
        gload_lds16(bsrc + (size_t)kb * BCHUNK + c * 4096 + w * 1024 + lane * 16,
                    nxt + ABYTES + c * 4096 + w * 1024);
      va = *(const f32x4*)(asrc0 + kb * 32);
      vb = *(const f32x4*)(asrc0 + kb * 32 + 16);
      vc = *(const f32x4*)(asrc1 + kb * 32);
      vd = *(const f32x4*)(asrc1 + kb * 32 + 16);
    }
    bf16x8 bfr[4], afr[8];
#pragma unroll
    for (int ct = 0; ct < 4; ++ct) bfr[ct] = *(const bf16x8*)(cur + boff[ct]);
#pragma unroll
    for (int rt = 0; rt < 8; ++rt) afr[rt] = *(const bf16x8*)(cur + aoff[rt]);
#pragma unroll
    for (int rt = 0; rt < 8; ++rt)
#pragma unroll
      for (int ct = 0; ct < 4; ++ct)
        acc[rt][ct] = __builtin_amdgcn_mfma_f32_16x16x32_bf16(afr[rt], bfr[ct],
                                                              acc[rt][ct], 0, 0, 0);
    if (step < 31) {
      u32x2 lo0 = packbf(va), hi0 = packbf(vb), lo1 = packbf(vc), hi1 = packbf(vd);
      u32x4 w0; w0.x = lo0.x; w0.y = lo0.y; w0.z = hi0.x; w0.w = hi0.y;
      u32x4 w1; w1.x = lo1.x; w1.y = lo1.y; w1.z = hi1.x; w1.w = hi1.y;
      *(u32x4*)(nxt + aw0) = w0;
      *(u32x4*)(nxt + aw1) = w1;
    }
    __syncthreads();
  }

  // epilogue: h = relu(acc + db), p = h·wf, reduce over this block's 256 cols
  float db[4], wv[4];
#pragma unroll
  for (int ct = 0; ct < 4; ++ct) {
    int a = split * NB_COLS + w * 64 + ct * 16 + nl;
    db[ct] = dcomb[bb * A_DIM + a];
    wv[ct] = wf[a];
  }
#pragma unroll
  for (int rt = 0; rt < 8; ++rt) {
#pragma unroll
    for (int r = 0; r < 4; ++r) {
      float p = 0.f;
#pragma unroll
      for (int ct = 0; ct < 4; ++ct) {
        float h = acc[rt][ct][r] + db[ct];
        h = h > 0.f ? h : 0.f;
        p += h * wv[ct];
      }
      p += __shfl_xor(p, 1);
      p += __shfl_xor(p, 2);
      p += __shfl_xor(p, 4);
      p += __shfl_xor(p, 8);
      if (nl == 0) atomicAdd(&s_score[rt * 16 + g * 4 + r], p);
    }
  }
  __syncthreads();
  if (tid < 128) atomicAdd(&scoreOut[row0 + tid], s_score[tid]);
}

// ---------------- K3: softmax over L per batch, in place ------------------------------------
__global__ void softmax_kernel(float* __restrict__ attn) {
  __shared__ float red[8];
  const int b = blockIdx.x, tid = threadIdx.x;
  float* p = attn + b * L_SEQ;
  float v[8];
  float m = -1e30f;
#pragma unroll
  for (int i = 0; i < 8; ++i) {
    v[i] = p[tid + i * 256];
    m = fmaxf(m, v[i]);
  }
#pragma unroll
  for (int off = 1; off < 64; off <<= 1) m = fmaxf(m, __shfl_xor(m, off));
  const int wid = tid >> 6;
  if ((tid & 63) == 0) red[wid] = m;
  __syncthreads();
  m = fmaxf(fmaxf(red[0], red[1]), fmaxf(red[2], red[3]));
  float s = 0.f;
#pragma unroll
  for (int i = 0; i < 8; ++i) {
    v[i] = __expf(v[i] - m);
    s += v[i];
  }
#pragma unroll
  for (int off = 1; off < 64; off <<= 1) s += __shfl_xor(s, off);
  __syncthreads();
  if ((tid & 63) == 0) red[4 + wid] = s;
  __syncthreads();
  const float inv = 1.0f / (red[4] + red[5] + red[6] + red[7]);
#pragma unroll
  for (int i = 0; i < 8; ++i) p[tid + i * 256] = v[i] * inv;
}

// ---------------- K4: weighted[b][e] = sum_l alpha[b][l] * enc[b][l][e] ---------------------
__global__ void weighted_kernel(const float* __restrict__ enc, const float* __restrict__ alpha,
                                float* __restrict__ outW) {
  __shared__ float sa[256];
  const int bid = blockIdx.x;  // 512 = 64 b * 8 l-segments
  const int b = bid >> 3, ls = bid & 7;
  const int tid = threadIdx.x;
  sa[tid] = alpha[b * L_SEQ + ls * 256 + tid];
  __syncthreads();
  const f32x4* ep = (const f32x4*)(enc + ((size_t)(b * L_SEQ + ls * 256)) * E_DIM) + tid;
  f32x4 acc = {0.f, 0.f, 0.f, 0.f};
#pragma unroll 8
  for (int il = 0; il < 256; ++il) {
    f32x4 v = ep[(size_t)il * 256];
    float al = sa[il];
    acc.x += al * v.x;
    acc.y += al * v.y;
    acc.z += al * v.z;
    acc.w += al * v.w;
  }
  float* o = outW + b * E_DIM + tid * 4;
  atomicAdd(o + 0, acc.x);
  atomicAdd(o + 1, acc.y);
  atomicAdd(o + 2, acc.z);
  atomicAdd(o + 3, acc.w);
}

extern "C" void kernel_launch(void* const* d_in, const int* in_sizes, int n_in,
                              void* d_out, int out_size, void* d_ws, size_t ws_size,
                              hipStream_t stream) {
  const float* enc = (const float*)d_in[0];
  const float* dh = (const float*)d_in[1];
  const float* WeW = (const float*)d_in[2];
  const float* WeB = (const float*)d_in[3];
  const float* WdW = (const float*)d_in[4];
  const float* WdB = (const float*)d_in[5];
  const float* WfW = (const float*)d_in[6];
  // Wf_b (d_in[7]) is irrelevant: softmax is shift-invariant and attn isn't an output.

  float* out = (float*)d_out;
  float* outW = out;                      // weighted: 64*1024
  float* attn = out + B_BATCH * E_DIM;    // scores -> alpha: 64*2048

  char* wsB = (char*)d_ws;                                     // 32 * 40960 = 1.25 MB
  float* dcomb = (float*)((char*)d_ws + 32 * (size_t)BCHUNK);  // 64*512 fp32

  if (ws_size < 32 * (size_t)BCHUNK + (size_t)B_BATCH * A_DIM * sizeof(float)) return;

  // zero weighted-output AND the score accumulator (GEMM now atomically adds partials)
  hipMemsetAsync(out, 0, (size_t)(B_BATCH * E_DIM + B_BATCH * L_SEQ) * sizeof(float), stream);
  prep_we_kernel<<<512, 256, 0, stream>>>(WeW, wsB);
  dec_comb_kernel<<<dim3(B_BATCH, 2), 256, 0, stream>>>(dh, WdW, WdB, WeB, dcomb);
  score_gemm_kernel<<<(B_BATCH * L_SEQ) / 128 * 2, 256, 0, stream>>>(enc, wsB, dcomb, WfW, attn);
  softmax_kernel<<<B_BATCH, 256, 0, stream>>>(attn);
  weighted_kernel<<<B_BATCH * 8, 256, 0, stream>>>(enc, attn, outW);
}

// Round 3
// 408.457 us; speedup vs baseline: 1.3021x; 1.0631x over previous
//
#include <hip/hip_runtime.h>
#include <stdint.h>

#define B_BATCH 64
#define L_SEQ 2048
#define E_DIM 1024
#define A_DIM 512

typedef __attribute__((ext_vector_type(4))) float f32x4;
typedef __attribute__((ext_vector_type(8))) short bf16x8;
typedef __attribute__((ext_vector_type(2))) unsigned int u32x2;
typedef __attribute__((ext_vector_type(4))) unsigned int u32x4;

__device__ __forceinline__ unsigned short f2bf(float f) {
  unsigned u = __float_as_uint(f);
  u = (u + 0x7fffu + ((u >> 16) & 1u)) >> 16;  // RNE
  return (unsigned short)u;
}

__device__ __forceinline__ u32x2 packbf(f32x4 v) {
  u32x2 r;
  r.x = (unsigned)f2bf(v.x) | ((unsigned)f2bf(v.y) << 16);
  r.y = (unsigned)f2bf(v.z) | ((unsigned)f2bf(v.w) << 16);
  return r;
}

__device__ __forceinline__ void gload_lds16(const void* g, void* l) {
  __builtin_amdgcn_global_load_lds(
      (const __attribute__((address_space(1))) unsigned int*)(uintptr_t)g,
      (__attribute__((address_space(3))) unsigned int*)(unsigned)(uintptr_t)l,
      16, 0, 0);
}

// Layout: per K-step chunk (BK=32): B = 512 cols x 64 B (kperm'd, XOR-swizzled), 32 KB.
// LDS buffer = [B-half 16384][A 128 rows x 64 B = 8192] = 24576; 3 buffers.
// Swizzle: 16B slot s at row n lives at physical slot s ^ ((n>>1)&3).
// kperm within row: slot g holds k {4g..4g+3, 16+4g..16+4g+3} (8B units 2g, 2g+1).
#define BCHUNK 32768
#define BUFB 24576
#define ABASE 16384

// ---------------- K0: We_w (fp32 [1024,512]) -> ws_B bf16 pre-swizzled image ---------------
__global__ void prep_we_kernel(const float* __restrict__ We, char* __restrict__ wsB) {
  int t = blockIdx.x * 256 + threadIdx.x;  // 131072 threads
  int n = t & 511;
  int kgl = t >> 9;  // 0..255, e0 = kgl*4
  int e0 = kgl * 4;
  int kb = e0 >> 5;
  int kg = (e0 >> 2) & 7;
  unsigned lo = (unsigned)f2bf(We[(size_t)(e0 + 0) * A_DIM + n]) |
                ((unsigned)f2bf(We[(size_t)(e0 + 1) * A_DIM + n]) << 16);
  unsigned hi = (unsigned)f2bf(We[(size_t)(e0 + 2) * A_DIM + n]) |
                ((unsigned)f2bf(We[(size_t)(e0 + 3) * A_DIM + n]) << 16);
  u32x2 val; val.x = lo; val.y = hi;
  int slot = (kg & 3) ^ ((n >> 1) & 3);
  *(u32x2*)(wsB + (size_t)kb * BCHUNK + n * 64 + slot * 16 + (kg >> 2) * 8) = val;
}

// ---------------- K1: dcomb[b][a] = decoder_hidden[b]·Wd_w[:,a] + Wd_b[a] + We_b[a] --------
__global__ void dec_comb_kernel(const float* __restrict__ dh, const float* __restrict__ Wd,
                                const float* __restrict__ Wdb, const float* __restrict__ Web,
                                float* __restrict__ dcomb) {
  __shared__ float sh[1024];
  const int b = blockIdx.x, tid = threadIdx.x;
  for (int i = tid; i < 1024; i += 256) sh[i] = dh[b * 1024 + i];
  __syncthreads();
  const int a = blockIdx.y * 256 + tid;
  float acc = Wdb[a] + Web[a];
#pragma unroll 4
  for (int e = 0; e < 1024; ++e) acc += sh[e] * Wd[(size_t)e * A_DIM + a];
  dcomb[b * A_DIM + a] = acc;
}

// ---------------- K2: fused score GEMM, counted-vmcnt 3-buffer pipeline --------------------
// block: 128 rows x 256 cols, 4 waves, wave = 128x64. BK=32, 32 K-steps.
// Per iter t: issue B(t+1) gload_lds + A(t+2) global->reg; vmcnt(8); ds_write A(t+1);
// lgkmcnt(0); raw s_barrier; compute(t). Never vmcnt(0) until the tail.
__global__ __launch_bounds__(256, 2) void score_gemm_kernel(
    const float* __restrict__ enc, const char* __restrict__ wsB,
    const float* __restrict__ dcomb, const float* __restrict__ wf,
    float* __restrict__ scoreOut) {
  __shared__ __align__(16) char smem[3 * BUFB];
  __shared__ float s_score[128];

  const int tid = threadIdx.x;
  const int lane = tid & 63;
  const int w = tid >> 6;      // 0..3
  const int g = lane >> 4;
  const int nl = lane & 15;
  const int gs = g ^ ((nl >> 1) & 3);   // swizzled read slot (same for A and B tiles)

  // XCD swizzle: both col-splits of a row-block land on the same XCD, adjacent in time.
  const int bid = (int)blockIdx.x;
  const int lbid = (bid & 7) * 256 + (bid >> 3);
  const int split = lbid & 1;
  const int row0 = (lbid >> 1) * 128;
  const int bb = row0 >> 11;

  if (tid < 128) s_score[tid] = 0.0f;

  const float* encA = enc + (size_t)row0 * E_DIM;
  const char* bsrc = wsB + split * 16384;

  int aoff[8], boff[4];
#pragma unroll
  for (int rt = 0; rt < 8; ++rt) aoff[rt] = ABASE + (rt * 16 + nl) * 64 + gs * 16;
#pragma unroll
  for (int ct = 0; ct < 4; ++ct) boff[ct] = (w * 64 + ct * 16 + nl) * 64 + gs * 16;

  // A staging: thread -> rows (tid>>2, +64), 16B chunk ac = tid&3 (= kg pair {ac, ac+4})
  const int ar0 = tid >> 2, ac = tid & 3;
  const int aw0 = ABASE + ar0 * 64 + ((ac ^ ((ar0 >> 1) & 3)) * 16);
  const int aw1 = aw0 + 4096;  // row+64: same swizzle group
  const float* as0 = encA + (size_t)ar0 * E_DIM + ac * 4;
  const float* as1 = as0 + 64 * E_DIM;

  f32x4 acc[8][4];
#pragma unroll
  for (int rt = 0; rt < 8; ++rt)
#pragma unroll
    for (int ct = 0; ct < 4; ++ct) {
      f32x4 z = {0.f, 0.f, 0.f, 0.f};
      acc[rt][ct] = z;
    }
  f32x4 ra[2][4];

#define STAGE_B(kb_, dst_)                                                  \
  do {                                                                      \
    _Pragma("unroll") for (int c = 0; c < 4; ++c)                           \
        gload_lds16(bsrc + (size_t)(kb_)*BCHUNK + w * 4096 + c * 1024 +     \
                        lane * 16,                                          \
                    smem + (dst_) + w * 4096 + c * 1024);                   \
  } while (0)

#define LOAD_A(kb_, s_)                                 \
  do {                                                  \
    ra[s_][0] = *(const f32x4*)(as0 + (kb_)*32);        \
    ra[s_][1] = *(const f32x4*)(as0 + (kb_)*32 + 16);   \
    ra[s_][2] = *(const f32x4*)(as1 + (kb_)*32);        \
    ra[s_][3] = *(const f32x4*)(as1 + (kb_)*32 + 16);   \
  } while (0)

#define WRITE_A(s_, dst_)                                          \
  do {                                                             \
    u32x2 l0 = packbf(ra[s_][0]), h0 = packbf(ra[s_][1]);          \
    u32x2 l1 = packbf(ra[s_][2]), h1 = packbf(ra[s_][3]);          \
    u32x4 w0; w0.x = l0.x; w0.y = l0.y; w0.z = h0.x; w0.w = h0.y;  \
    u32x4 w1; w1.x = l1.x; w1.y = l1.y; w1.z = h1.x; w1.w = h1.y;  \
    *(u32x4*)(smem + (dst_) + aw0) = w0;                           \
    *(u32x4*)(smem + (dst_) + aw1) = w1;                           \
  } while (0)

#define COMPUTE(cur_)                                                        \
  do {                                                                       \
    bf16x8 bfr[4], afr[8];                                                   \
    _Pragma("unroll") for (int ct = 0; ct < 4; ++ct) bfr[ct] =               \
        *(const bf16x8*)(smem + (cur_) + boff[ct]);                          \
    _Pragma("unroll") for (int rt = 0; rt < 8; ++rt) afr[rt] =               \
        *(const bf16x8*)(smem + (cur_) + aoff[rt]);                          \
    __builtin_amdgcn_s_setprio(1);                                           \
    _Pragma("unroll") for (int rt = 0; rt < 8; ++rt)                         \
        _Pragma("unroll") for (int ct = 0; ct < 4; ++ct) acc[rt][ct] =       \
            __builtin_amdgcn_mfma_f32_16x16x32_bf16(afr[rt], bfr[ct],        \
                                                    acc[rt][ct], 0, 0, 0);   \
    __builtin_amdgcn_s_setprio(0);                                           \
  } while (0)

  // ---- prologue: A(0)->ra0, B(0)->buf0, A(1)->ra1; wait A(0); ds_write A(0)->buf0
  LOAD_A(0, 0);
  STAGE_B(0, 0);
  LOAD_A(1, 1);
  asm volatile("s_waitcnt vmcnt(8)" ::: "memory");
  WRITE_A(0, 0);

  int b0 = 0, b1 = BUFB, b2 = 2 * BUFB;
#pragma unroll 6
  for (int t = 0; t < 30; ++t) {
    STAGE_B(t + 1, b1);
    LOAD_A(t + 2, t & 1);
    asm volatile("s_waitcnt vmcnt(8)" ::: "memory");
    WRITE_A((t + 1) & 1, b1);
    asm volatile("s_waitcnt lgkmcnt(0)" ::: "memory");
    asm volatile("s_barrier" ::: "memory");
    COMPUTE(b0);
    int tmp = b0; b0 = b1; b1 = b2; b2 = tmp;
  }
  // ---- t = 30: stage B(31), no more A loads
  STAGE_B(31, b1);
  asm volatile("s_waitcnt vmcnt(4)" ::: "memory");
  WRITE_A(1, b1);
  asm volatile("s_waitcnt lgkmcnt(0)" ::: "memory");
  asm volatile("s_barrier" ::: "memory");
  COMPUTE(b0);
  { int tmp = b0; b0 = b1; b1 = b2; b2 = tmp; }
  // ---- t = 31
  asm volatile("s_waitcnt vmcnt(0) lgkmcnt(0)" ::: "memory");
  asm volatile("s_barrier" ::: "memory");
  COMPUTE(b0);

#undef STAGE_B
#undef LOAD_A
#undef WRITE_A
#undef COMPUTE

  // epilogue: h = relu(acc + db), p = h·wf, reduce over this block's 256 cols
  float db[4], wv[4];
#pragma unroll
  for (int ct = 0; ct < 4; ++ct) {
    int a = split * 256 + w * 64 + ct * 16 + nl;
    db[ct] = dcomb[bb * A_DIM + a];
    wv[ct] = wf[a];
  }
#pragma unroll
  for (int rt = 0; rt < 8; ++rt) {
#pragma unroll
    for (int r = 0; r < 4; ++r) {
      float p = 0.f;
#pragma unroll
      for (int ct = 0; ct < 4; ++ct) {
        float h = acc[rt][ct][r] + db[ct];
        h = h > 0.f ? h : 0.f;
        p += h * wv[ct];
      }
      p += __shfl_xor(p, 1);
      p += __shfl_xor(p, 2);
      p += __shfl_xor(p, 4);
      p += __shfl_xor(p, 8);
      if (nl == 0) atomicAdd(&s_score[rt * 16 + g * 4 + r], p);
    }
  }
  __syncthreads();
  if (tid < 128) atomicAdd(&scoreOut[row0 + tid], s_score[tid]);
}

// ---------------- K3: softmax over L per batch, in place -----------------------------------
__global__ void softmax_kernel(float* __restrict__ attn) {
  __shared__ float red[8];
  const int b = blockIdx.x, tid = threadIdx.x;
  float* p = attn + b * L_SEQ;
  float v[8];
  float m = -1e30f;
#pragma unroll
  for (int i = 0; i < 8; ++i) {
    v[i] = p[tid + i * 256];
    m = fmaxf(m, v[i]);
  }
#pragma unroll
  for (int off = 1; off < 64; off <<= 1) m = fmaxf(m, __shfl_xor(m, off));
  const int wid = tid >> 6;
  if ((tid & 63) == 0) red[wid] = m;
  __syncthreads();
  m = fmaxf(fmaxf(red[0], red[1]), fmaxf(red[2], red[3]));
  float s = 0.f;
#pragma unroll
  for (int i = 0; i < 8; ++i) {
    v[i] = __expf(v[i] - m);
    s += v[i];
  }
#pragma unroll
  for (int off = 1; off < 64; off <<= 1) s += __shfl_xor(s, off);
  __syncthreads();
  if ((tid & 63) == 0) red[4 + wid] = s;
  __syncthreads();
  const float inv = 1.0f / (red[4] + red[5] + red[6] + red[7]);
#pragma unroll
  for (int i = 0; i < 8; ++i) p[tid + i * 256] = v[i] * inv;
}

// ---------------- K4: weighted[b][e] = sum_l alpha[b][l] * enc[b][l][e] --------------------
__global__ void weighted_kernel(const float* __restrict__ enc, const float* __restrict__ alpha,
                                float* __restrict__ outW) {
  __shared__ float sa[64];
  const int bid = blockIdx.x;  // 2048 = 64 b * 32 l-segments of 64
  const int b = bid >> 5, ls = bid & 31;
  const int tid = threadIdx.x;
  if (tid < 64) sa[tid] = alpha[b * L_SEQ + ls * 64 + tid];
  __syncthreads();
  const f32x4* ep = (const f32x4*)(enc + ((size_t)(b * L_SEQ + ls * 64)) * E_DIM) + tid;
  f32x4 acc = {0.f, 0.f, 0.f, 0.f};
#pragma unroll 8
  for (int il = 0; il < 64; ++il) {
    f32x4 v = ep[(size_t)il * 256];
    float al = sa[il];
    acc.x += al * v.x;
    acc.y += al * v.y;
    acc.z += al * v.z;
    acc.w += al * v.w;
  }
  float* o = outW + b * E_DIM + tid * 4;
  atomicAdd(o + 0, acc.x);
  atomicAdd(o + 1, acc.y);
  atomicAdd(o + 2, acc.z);
  atomicAdd(o + 3, acc.w);
}

extern "C" void kernel_launch(void* const* d_in, const int* in_sizes, int n_in,
                              void* d_out, int out_size, void* d_ws, size_t ws_size,
                              hipStream_t stream) {
  const float* enc = (const float*)d_in[0];
  const float* dh = (const float*)d_in[1];
  const float* WeW = (const float*)d_in[2];
  const float* WeB = (const float*)d_in[3];
  const float* WdW = (const float*)d_in[4];
  const float* WdB = (const float*)d_in[5];
  const float* WfW = (const float*)d_in[6];
  // Wf_b (d_in[7]) irrelevant: softmax is shift-invariant and attn isn't an output.

  float* out = (float*)d_out;
  float* outW = out;                      // weighted: 64*1024
  float* attn = out + B_BATCH * E_DIM;    // scores -> alpha: 64*2048

  char* wsB = (char*)d_ws;                                     // 32 * 32768 = 1 MB
  float* dcomb = (float*)((char*)d_ws + 32 * (size_t)BCHUNK);  // 64*512 fp32

  if (ws_size < 32 * (size_t)BCHUNK + (size_t)B_BATCH * A_DIM * sizeof(float)) return;

  hipMemsetAsync(out, 0, (size_t)(B_BATCH * E_DIM + B_BATCH * L_SEQ) * sizeof(float), stream);
  prep_we_kernel<<<512, 256, 0, stream>>>(WeW, wsB);
  dec_comb_kernel<<<dim3(B_BATCH, 2), 256, 0, stream>>>(dh, WdW, WdB, WeB, dcomb);
  score_gemm_kernel<<<(B_BATCH * L_SEQ) / 128 * 2, 256, 0, stream>>>(enc, wsB, dcomb, WfW, attn);
  softmax_kernel<<<B_BATCH, 256, 0, stream>>>(attn);
  weighted_kernel<<<B_BATCH * 32, 256, 0, stream>>>(enc, attn, outW);
}

// Round 5
// 384.498 us; speedup vs baseline: 1.3833x; 1.0623x over previous
//
#include <hip/hip_runtime.h>
#include <stdint.h>

#define B_BATCH 64
#define L_SEQ 2048
#define E_DIM 1024
#define A_DIM 512

typedef __attribute__((ext_vector_type(4))) float f32x4;
typedef __attribute__((ext_vector_type(8))) short bf16x8;
typedef __attribute__((ext_vector_type(2))) unsigned int u32x2;
typedef __attribute__((ext_vector_type(4))) unsigned int u32x4;

__device__ __forceinline__ unsigned short f2bf(float f) {
  unsigned u = __float_as_uint(f);
  u = (u + 0x7fffu + ((u >> 16) & 1u)) >> 16;  // RNE
  return (unsigned short)u;
}

__device__ __forceinline__ u32x2 packbf(f32x4 v) {
  u32x2 r;
  r.x = (unsigned)f2bf(v.x) | ((unsigned)f2bf(v.y) << 16);
  r.y = (unsigned)f2bf(v.z) | ((unsigned)f2bf(v.w) << 16);
  return r;
}

// A-tile LDS image: 128 rows x 64 B (32 bf16). 16B slot s of row n at slot s ^ ((n>>1)&3).
// Slot g holds k {4g..4g+3, 16+4g..16+4g+3} (the 16x16x32 frag k-order, proven R1-R3).
// 3 buffers of 8 KB.
#define BUFB 8192
#define BCHUNK 32768  // ws_B bytes per K-step: 512 cols x 64 B frag-chunks

// ---------------- K0: We_w (fp32 [1024,512]) -> ws_B bf16 in GEMM B-frag order -------------
// chunk (step, colblk 0..31, lane 0..63) at byte step*32768 + colblk*1024 + lane*16:
// col = colblk*16 + (lane&15), g = lane>>4, k = step*32 + {4g..4g+3, 16+4g..16+4g+3}.
// 65536 chunks total -> 256 blocks x 256 threads, one 16B chunk per thread.
__global__ void prep_we_kernel(const float* __restrict__ We, char* __restrict__ wsB) {
  int t = blockIdx.x * 256 + threadIdx.x;  // 65536 threads = 1 chunk each
  int lane = t & 63;
  int colblk = (t >> 6) & 31;
  int step = t >> 11;  // 0..31
  int nl = lane & 15, g = lane >> 4;
  int col = colblk * 16 + nl;
  int k0 = step * 32 + 4 * g;
  unsigned q0 = (unsigned)f2bf(We[(size_t)(k0 + 0) * A_DIM + col]) |
                ((unsigned)f2bf(We[(size_t)(k0 + 1) * A_DIM + col]) << 16);
  unsigned q1 = (unsigned)f2bf(We[(size_t)(k0 + 2) * A_DIM + col]) |
                ((unsigned)f2bf(We[(size_t)(k0 + 3) * A_DIM + col]) << 16);
  unsigned q2 = (unsigned)f2bf(We[(size_t)(k0 + 16) * A_DIM + col]) |
                ((unsigned)f2bf(We[(size_t)(k0 + 17) * A_DIM + col]) << 16);
  unsigned q3 = (unsigned)f2bf(We[(size_t)(k0 + 18) * A_DIM + col]) |
                ((unsigned)f2bf(We[(size_t)(k0 + 19) * A_DIM + col]) << 16);
  u32x4 v; v.x = q0; v.y = q1; v.z = q2; v.w = q3;
  *(u32x4*)(wsB + (size_t)t * 16) = v;
}

// ---------------- K1: dcomb[b][a] = decoder_hidden[b]·Wd_w[:,a] + Wd_b[a] + We_b[a] --------
__global__ void dec_comb_kernel(const float* __restrict__ dh, const float* __restrict__ Wd,
                                const float* __restrict__ Wdb, const float* __restrict__ Web,
                                float* __restrict__ dcomb) {
  __shared__ float sh[1024];
  const int b = blockIdx.x, tid = threadIdx.x;
  for (int i = tid; i < 1024; i += 256) sh[i] = dh[b * 1024 + i];
  __syncthreads();
  const int a = blockIdx.y * 256 + tid;
  float acc = Wdb[a] + Web[a];
#pragma unroll 4
  for (int e = 0; e < 1024; ++e) acc += sh[e] * Wd[(size_t)e * A_DIM + a];
  dcomb[b * A_DIM + a] = acc;
}

// ---------------- K2: fused score GEMM -----------------------------------------------------
// block: 128 rows x 512 cols, 8 waves (512 thr), wave = 128x64. BK=32, 32 K-steps.
// A: global fp32 -> reg -> bf16 -> LDS (3-buffer, swizzled). B: global bf16 frags -> reg,
// prefetch depth 1 (L2-resident). Per iter: 2 A-loads + 4 B-loads; vmcnt(6); ds_write A;
// lgkmcnt(0); raw s_barrier; MFMA. Never vmcnt(0) until the tail.
__global__ __launch_bounds__(512, 2) void score_gemm_kernel(
    const float* __restrict__ enc, const char* __restrict__ wsB,
    const float* __restrict__ dcomb, const float* __restrict__ wf,
    float* __restrict__ scoreOut) {
  __shared__ __align__(16) char smem[3 * BUFB];
  __shared__ float s_score[128];

  const int tid = threadIdx.x;
  const int lane = tid & 63;
  const int w = tid >> 6;      // 0..7
  const int g = lane >> 4;
  const int nl = lane & 15;
  const int gs = g ^ ((nl >> 1) & 3);   // swizzled read slot

  const int row0 = (int)blockIdx.x * 128;
  const int bb = row0 >> 11;

  if (tid < 128) s_score[tid] = 0.0f;

  const float* encA = enc + (size_t)row0 * E_DIM;

  int aoff[8];
#pragma unroll
  for (int rt = 0; rt < 8; ++rt) aoff[rt] = (rt * 16 + nl) * 64 + gs * 16;

  // A staging: thread -> (row ar = tid>>2, slot g' = tid&3): 8 floats
  // cols {4g'..4g'+3} and {16+4g'..16+4g'+3} -> one 16B bf16 chunk.
  const int ar = tid >> 2, ag = tid & 3;
  const int aw = ar * 64 + ((ag ^ ((ar >> 1) & 3)) * 16);
  const float* asrc = encA + (size_t)ar * E_DIM + ag * 4;

  // B frags: wave w reads chunks (w*4 + ct)*1024 + lane*16 per step
  const char* bsrc = wsB + (w * 4) * 1024 + lane * 16;

  f32x4 acc[8][4];
#pragma unroll
  for (int rt = 0; rt < 8; ++rt)
#pragma unroll
    for (int ct = 0; ct < 4; ++ct) {
      f32x4 z = {0.f, 0.f, 0.f, 0.f};
      acc[rt][ct] = z;
    }
  f32x4 ra[2][2];
  bf16x8 bfr[2][4];

#define LOAD_A(kb_, s_)                                  \
  do {                                                   \
    ra[s_][0] = *(const f32x4*)(asrc + (kb_) * 32);      \
    ra[s_][1] = *(const f32x4*)(asrc + (kb_) * 32 + 16); \
  } while (0)

#define LOAD_B(kb_, s_)                                                     \
  do {                                                                      \
    _Pragma("unroll") for (int ct = 0; ct < 4; ++ct) bfr[s_][ct] =          \
        *(const bf16x8*)(bsrc + (size_t)(kb_)*BCHUNK + ct * 1024);          \
  } while (0)

#define WRITE_A(s_, dst_)                                          \
  do {                                                             \
    u32x2 l0 = packbf(ra[s_][0]);                                  \
    u32x2 h0 = packbf(ra[s_][1]);                                  \
    u32x4 w0; w0.x = l0.x; w0.y = l0.y; w0.z = h0.x; w0.w = h0.y;  \
    *(u32x4*)(smem + (dst_) + aw) = w0;                            \
  } while (0)

#define COMPUTE(cur_, s_)                                                    \
  do {                                                                       \
    bf16x8 afr[8];                                                           \
    _Pragma("unroll") for (int rt = 0; rt < 8; ++rt) afr[rt] =               \
        *(const bf16x8*)(smem + (cur_) + aoff[rt]);                          \
    __builtin_amdgcn_s_setprio(1);                                           \
    _Pragma("unroll") for (int rt = 0; rt < 8; ++rt)                         \
        _Pragma("unroll") for (int ct = 0; ct < 4; ++ct) acc[rt][ct] =       \
            __builtin_amdgcn_mfma_f32_16x16x32_bf16(afr[rt], bfr[s_][ct],    \
                                                    acc[rt][ct], 0, 0, 0);   \
    __builtin_amdgcn_s_setprio(0);                                           \
  } while (0)

  // ---- prologue: A0 -> ra0, A1 -> ra1, B0 -> bfr0; wait A0; write A0 -> buf0
  LOAD_A(0, 0);
  LOAD_A(1, 1);
  LOAD_B(0, 0);
  asm volatile("s_waitcnt vmcnt(6)" ::: "memory");
  WRITE_A(0, 0);

  int b0 = 0, b1 = BUFB, b2 = 2 * BUFB;
#pragma unroll 6
  for (int t = 0; t < 30; ++t) {
    LOAD_A(t + 2, t & 1);
    LOAD_B(t + 1, (t + 1) & 1);
    asm volatile("s_waitcnt vmcnt(6)" ::: "memory");  // completes A(t+1), B(t)
    WRITE_A((t + 1) & 1, b1);
    asm volatile("s_waitcnt lgkmcnt(0)" ::: "memory");
    asm volatile("s_barrier" ::: "memory");
    COMPUTE(b0, t & 1);
    int tmp = b0; b0 = b1; b1 = b2; b2 = tmp;
  }
  // ---- t = 30: last B prefetch, A31 already in flight
  LOAD_B(31, 1);
  asm volatile("s_waitcnt vmcnt(4)" ::: "memory");  // completes A31, B30
  WRITE_A(1, b1);
  asm volatile("s_waitcnt lgkmcnt(0)" ::: "memory");
  asm volatile("s_barrier" ::: "memory");
  COMPUTE(b0, 0);
  { int tmp = b0; b0 = b1; b1 = b2; b2 = tmp; }
  // ---- t = 31
  asm volatile("s_waitcnt vmcnt(0) lgkmcnt(0)" ::: "memory");
  asm volatile("s_barrier" ::: "memory");
  COMPUTE(b0, 1);

#undef LOAD_A
#undef LOAD_B
#undef WRITE_A
#undef COMPUTE

  // epilogue: h = relu(acc + db), p = h·wf, reduce over 512 cols
  float db[4], wv[4];
#pragma unroll
  for (int ct = 0; ct < 4; ++ct) {
    int a = w * 64 + ct * 16 + nl;
    db[ct] = dcomb[bb * A_DIM + a];
    wv[ct] = wf[a];
  }
#pragma unroll
  for (int rt = 0; rt < 8; ++rt) {
#pragma unroll
    for (int r = 0; r < 4; ++r) {
      float p = 0.f;
#pragma unroll
      for (int ct = 0; ct < 4; ++ct) {
        float h = acc[rt][ct][r] + db[ct];
        h = h > 0.f ? h : 0.f;
        p += h * wv[ct];
      }
      p += __shfl_xor(p, 1);
      p += __shfl_xor(p, 2);
      p += __shfl_xor(p, 4);
      p += __shfl_xor(p, 8);
      if (nl == 0) atomicAdd(&s_score[rt * 16 + g * 4 + r], p);
    }
  }
  __syncthreads();
  if (tid < 128) scoreOut[row0 + tid] = s_score[tid];
}

// ---------------- K3: softmax over L per batch, in place -----------------------------------
__global__ void softmax_kernel(float* __restrict__ attn) {
  __shared__ float red[8];
  const int b = blockIdx.x, tid = threadIdx.x;
  float* p = attn + b * L_SEQ;
  float v[8];
  float m = -1e30f;
#pragma unroll
  for (int i = 0; i < 8; ++i) {
    v[i] = p[tid + i * 256];
    m = fmaxf(m, v[i]);
  }
#pragma unroll
  for (int off = 1; off < 64; off <<= 1) m = fmaxf(m, __shfl_xor(m, off));
  const int wid = tid >> 6;
  if ((tid & 63) == 0) red[wid] = m;
  __syncthreads();
  m = fmaxf(fmaxf(red[0], red[1]), fmaxf(red[2], red[3]));
  float s = 0.f;
#pragma unroll
  for (int i = 0; i < 8; ++i) {
    v[i] = __expf(v[i] - m);
    s += v[i];
  }
#pragma unroll
  for (int off = 1; off < 64; off <<= 1) s += __shfl_xor(s, off);
  __syncthreads();
  if ((tid & 63) == 0) red[4 + wid] = s;
  __syncthreads();
  const float inv = 1.0f / (red[4] + red[5] + red[6] + red[7]);
#pragma unroll
  for (int i = 0; i < 8; ++i) p[tid + i * 256] = v[i] * inv;
}

// ---------------- K4: weighted[b][e] = sum_l alpha[b][l] * enc[b][l][e] --------------------
__global__ void weighted_kernel(const float* __restrict__ enc, const float* __restrict__ alpha,
                                float* __restrict__ outW) {
  __shared__ float sa[64];
  const int bid = blockIdx.x;  // 2048 = 64 b * 32 l-segments of 64
  const int b = bid >> 5, ls = bid & 31;
  const int tid = threadIdx.x;
  if (tid < 64) sa[tid] = alpha[b * L_SEQ + ls * 64 + tid];
  __syncthreads();
  const f32x4* ep = (const f32x4*)(enc + ((size_t)(b * L_SEQ + ls * 64)) * E_DIM) + tid;
  f32x4 acc = {0.f, 0.f, 0.f, 0.f};
#pragma unroll 8
  for (int il = 0; il < 64; ++il) {
    f32x4 v = ep[(size_t)il * 256];
    float al = sa[il];
    acc.x += al * v.x;
    acc.y += al * v.y;
    acc.z += al * v.z;
    acc.w += al * v.w;
  }
  float* o = outW + b * E_DIM + tid * 4;
  atomicAdd(o + 0, acc.x);
  atomicAdd(o + 1, acc.y);
  atomicAdd(o + 2, acc.z);
  atomicAdd(o + 3, acc.w);
}

extern "C" void kernel_launch(void* const* d_in, const int* in_sizes, int n_in,
                              void* d_out, int out_size, void* d_ws, size_t ws_size,
                              hipStream_t stream) {
  const float* enc = (const float*)d_in[0];
  const float* dh = (const float*)d_in[1];
  const float* WeW = (const float*)d_in[2];
  const float* WeB = (const float*)d_in[3];
  const float* WdW = (const float*)d_in[4];
  const float* WdB = (const float*)d_in[5];
  const float* WfW = (const float*)d_in[6];
  // Wf_b (d_in[7]) irrelevant: softmax is shift-invariant and attn isn't an output.

  float* out = (float*)d_out;
  float* outW = out;                      // weighted: 64*1024
  float* attn = out + B_BATCH * E_DIM;    // scores -> alpha: 64*2048

  char* wsB = (char*)d_ws;                                     // 32 * 32768 = 1 MB
  float* dcomb = (float*)((char*)d_ws + 32 * (size_t)BCHUNK);  // 64*512 fp32

  if (ws_size < 32 * (size_t)BCHUNK + (size_t)B_BATCH * A_DIM * sizeof(float)) return;

  hipMemsetAsync(outW, 0, (size_t)(B_BATCH * E_DIM) * sizeof(float), stream);
  prep_we_kernel<<<256, 256, 0, stream>>>(WeW, wsB);
  dec_comb_kernel<<<dim3(B_BATCH, 2), 256, 0, stream>>>(dh, WdW, WdB, WeB, dcomb);
  score_gemm_kernel<<<(B_BATCH * L_SEQ) / 128, 512, 0, stream>>>(enc, wsB, dcomb, WfW, attn);
  softmax_kernel<<<B_BATCH, 256, 0, stream>>>(attn);
  weighted_kernel<<<B_BATCH * 32, 256, 0, stream>>>(enc, attn, outW);
}